// Round 7
// baseline (2678.796 us; speedup 1.0000x reference)
//
#include <hip/hip_runtime.h>

typedef unsigned long long u64;
typedef unsigned int u32;
typedef float f32x2 __attribute__((ext_vector_type(2)));

constexpr int BATCH  = 8;
constexpr int NPTS   = 8192;
constexpr int CIN    = 64;
constexpr int COUT   = 128;
constexpr int NPOINT = 2048;
constexpr int KNN    = 16;

// ---------------------------------------------------------------------------
// pp kernel: per-point squared norm, same op order as reference sum(xyz**2)
// ---------------------------------------------------------------------------
__global__ __launch_bounds__(256) void pp_kernel(const float* __restrict__ xyz,
                                                 float* __restrict__ pp) {
  int i = blockIdx.x * 256 + threadIdx.x;  // 0..65535 (B*N)
  float x = xyz[i * 3 + 0], y = xyz[i * 3 + 1], z = xyz[i * 3 + 2];
  pp[i] = __fadd_rn(__fadd_rn(__fmul_rn(x, x), __fmul_rn(y, y)), __fmul_rn(z, z));
}

// ---------------------------------------------------------------------------
// FPS v6: one block per batch, 256 threads (4 waves, 1/EU).
// R6 post-mortem: VGPR_Count=132 vs ~190-reg working set (128 regs of point
// arrays + asm temps) => the loop was spilling/rematerializing every step;
// scratch stays L1/L2-resident so it never showed in FETCH_SIZE, only in
// issue cycles (active-CU VALUBusy ~62% = ~1500cy/step vs ~650 modeled).
// v6: __launch_bounds__(256,1) -> 1 wave/EU -> 512-VGPR budget, arrays+temps
// fully register-resident (LDS 152KB already limits to 1 block/CU, so the
// occupancy declaration costs nothing). Plus grouped argmax recovery:
// 4 independent group-max chains (v_max3-fusable) in pass 1; pass 2 scans
// groups with static indices only (no dynamic reg indexing -> no scratch),
// chains 8-deep instead of 32. pk inline-asm distance math unchanged
// (bitwise == scalar rn ops == XLA elementwise (dx*dx+dy*dy)+dz*dz).
// Key = (d_bits<<32 | 8191-idx): u64 max == (max d, tie -> min idx) ==
// jnp.argmax exactly. DPP reduce + parity-slot single barrier unchanged.
// ---------------------------------------------------------------------------
constexpr int FPS_T = 256;
constexpr int FPS_PAIRS = NPTS / FPS_T / 2;  // 16 pairs = 32 pts/thread

static __device__ __forceinline__ f32x2 pk_sub(f32x2 a, f32x2 b) {
  f32x2 r;
  asm("v_pk_add_f32 %0, %1, %2 neg_lo:[0,1] neg_hi:[0,1]"
      : "=v"(r) : "v"(a), "v"(b));
  return r;
}
static __device__ __forceinline__ f32x2 pk_mul(f32x2 a, f32x2 b) {
  f32x2 r;
  asm("v_pk_mul_f32 %0, %1, %2" : "=v"(r) : "v"(a), "v"(b));
  return r;
}
static __device__ __forceinline__ f32x2 pk_add(f32x2 a, f32x2 b) {
  f32x2 r;
  asm("v_pk_add_f32 %0, %1, %2" : "=v"(r) : "v"(a), "v"(b));
  return r;
}

#define DPP_LVL(CTRL)                                                          \
  {                                                                            \
    u32 hi_o = (u32)__builtin_amdgcn_update_dpp((int)khi, (int)khi, (CTRL),    \
                                                0xf, 0xf, false);              \
    u32 lo_o = (u32)__builtin_amdgcn_update_dpp((int)klo, (int)klo, (CTRL),    \
                                                0xf, 0xf, false);              \
    bool gt = (hi_o > khi) || ((hi_o == khi) && (lo_o > klo));                 \
    khi = gt ? hi_o : khi;                                                     \
    klo = gt ? lo_o : klo;                                                     \
  }

__global__ __launch_bounds__(256, 1) void fps_kernel(const float* __restrict__ xyz,
                                                     float* __restrict__ out_xyz) {
  __shared__ float4 sP[NPTS];          // 128 KB
  __shared__ float sOut[NPOINT * 3];   // 24 KB  (total 152.1 KB of 160 KB)
  __shared__ u64 sKey[2][4];
  const int b = blockIdx.x;
  const int t = threadIdx.x;
  const int lane = t & 63;
  const int wv = t >> 6;
  const float* xb = xyz + (size_t)b * NPTS * 3;
  f32x2 px2[FPS_PAIRS], py2[FPS_PAIRS], pz2[FPS_PAIRS], pd2[FPS_PAIRS];
#pragma unroll
  for (int jp = 0; jp < FPS_PAIRS; ++jp) {
    int p0 = t + (2 * jp) * FPS_T;      // idx ascending with (jp, half)
    int p1 = t + (2 * jp + 1) * FPS_T;
    float x0 = xb[p0 * 3 + 0], y0 = xb[p0 * 3 + 1], z0 = xb[p0 * 3 + 2];
    float x1 = xb[p1 * 3 + 0], y1 = xb[p1 * 3 + 1], z1 = xb[p1 * 3 + 2];
    px2[jp] = (f32x2){x0, x1};
    py2[jp] = (f32x2){y0, y1};
    pz2[jp] = (f32x2){z0, z1};
    pd2[jp] = (f32x2){1e10f, 1e10f};
    sP[p0] = make_float4(x0, y0, z0, 0.f);
    sP[p1] = make_float4(x1, y1, z1, 0.f);
  }
  float cx = xb[0], cy = xb[1], cz = xb[2];  // seed point index 0
  float* outx = out_xyz + (size_t)b * NPOINT * 3;
  __syncthreads();
  for (int it = 0; it < NPOINT; ++it) {
    if (t == 0) {  // scan emits the carry (current farthest); LDS-staged
      sOut[it * 3 + 0] = cx; sOut[it * 3 + 1] = cy; sOut[it * 3 + 2] = cz;
    }
    const f32x2 cx2 = {cx, cx}, cy2 = {cy, cy}, cz2 = {cz, cz};
    // pass 1: min-update + 4 independent group-max chains (ILP, max3-fusable)
    float gm[4] = {-1.0f, -1.0f, -1.0f, -1.0f};
#pragma unroll
    for (int jp = 0; jp < FPS_PAIRS; ++jp) {
      f32x2 dx = pk_sub(px2[jp], cx2);
      f32x2 dy = pk_sub(py2[jp], cy2);
      f32x2 dz = pk_sub(pz2[jp], cz2);
      f32x2 d = pk_add(pk_add(pk_mul(dx, dx), pk_mul(dy, dy)), pk_mul(dz, dz));
      f32x2 nd = __builtin_elementwise_min(pd2[jp], d);
      pd2[jp] = nd;
      const int g = jp >> 2;
      gm[g] = fmaxf(fmaxf(gm[g], nd.x), nd.y);  // v_max3_f32
    }
    const float bd = fmaxf(fmaxf(gm[0], gm[1]), fmaxf(gm[2], gm[3]));
    // pass 2: per-group smallest-j match (static reg indices only), then
    // ascending-priority group select. bd is bit-exactly one of the nd
    // values, so == compares are sound; smallest j / smallest group wins
    // == jnp.argmax tie rule (idx = t + j*FPS_T is ascending in j).
    int bjg[4];
#pragma unroll
    for (int g = 0; g < 4; ++g) {
      int bj = 0;
#pragma unroll
      for (int k = 3; k >= 0; --k) {
        const int jp = 4 * g + k;
        if (pd2[jp].y == gm[g]) bj = 2 * jp + 1;
        if (pd2[jp].x == gm[g]) bj = 2 * jp;
      }
      bjg[g] = bj;
    }
    int bj = bjg[3];
    if (gm[2] == bd) bj = bjg[2];
    if (gm[1] == bd) bj = bjg[1];
    if (gm[0] == bd) bj = bjg[0];
    const int bi0 = t + bj * FPS_T;
    u32 khi = __float_as_uint(bd);    // d>=0 -> bits monotone in d
    u32 klo = (u32)(8191 - bi0);      // tie -> larger klo == smaller idx
    // 6-level DPP directional max-reduce; full-wave max lands in lane 63
    DPP_LVL(0x111)  // row_shr:1
    DPP_LVL(0x112)  // row_shr:2
    DPP_LVL(0x114)  // row_shr:4
    DPP_LVL(0x118)  // row_shr:8
    DPP_LVL(0x142)  // row_bcast15
    DPP_LVL(0x143)  // row_bcast31
    const int par = it & 1;
    if (lane == 63) sKey[par][wv] = ((u64)khi << 32) | klo;
    __syncthreads();
    // all threads redundantly merge the 4 wave candidates (single barrier;
    // parity slots make the pipeline race-free)
    u64 k0 = sKey[par][0];
    u64 k1 = sKey[par][1];
    u64 k2 = sKey[par][2];
    u64 k3 = sKey[par][3];
    if (k1 > k0) k0 = k1;
    if (k3 > k2) k2 = k3;
    if (k2 > k0) k0 = k2;
    const int bi = 8191 - (int)(u32)(k0 & 0xFFFFFFFFu);
    float4 c4 = sP[bi];  // one ds_read_b128 broadcast
    cx = c4.x; cy = c4.y; cz = c4.z;
  }
  __syncthreads();
  // one coalesced dump of the staged output
  for (int i = t; i < NPOINT * 3; i += FPS_T) outx[i] = sOut[i];
}

// ---------------------------------------------------------------------------
// kNN: block = 64 queries (one batch) x 8 chunk-waves (1024 pts each).
// Point data is wave-uniform -> scalar loads. Per-lane sorted top-16 in regs
// (packed u64: orderable-float-bits<<32 | idx, so compare = (d, idx) lexico),
// with deferred LDS candidate buffer + wave-collective flush to avoid
// per-point divergent insert ladders. Distance mimics reference expansion
// -2*q.p + |q|^2 + |p|^2 with rn ops.
// ---------------------------------------------------------------------------
__global__ __launch_bounds__(512) void knn_kernel(const float* __restrict__ xyz,
                                                  const float* __restrict__ pp,
                                                  const float* __restrict__ new_xyz,
                                                  int* __restrict__ knn_idx) {
  __shared__ u64 smem[8192];  // 64KB. scan: Bf[512][9] (padded); merge: Ls[512][16]
  const int tid = threadIdx.x;
  const int lane = tid & 63;
  const int wv = __builtin_amdgcn_readfirstlane(tid >> 6);  // chunk id, forced scalar
  const int bid = blockIdx.x;
  const int b = bid >> 5;               // 32 query-blocks per batch
  const int qbase = (bid & 31) * 64;
  const int q = qbase + lane;
  const float* xb = xyz + (size_t)b * NPTS * 3;
  const float* ppb = pp + (size_t)b * NPTS;
  const float* nq = new_xyz + ((size_t)b * NPOINT + q) * 3;
  float qx = nq[0], qy = nq[1], qz = nq[2];
  float qq = __fadd_rn(__fadd_rn(__fmul_rn(qx, qx), __fmul_rn(qy, qy)),
                       __fmul_rn(qz, qz));

  u64 L[16];
#pragma unroll
  for (int s = 0; s < 16; ++s) L[s] = 0xFF800000FFFFFFFFULL;  // +inf sentinel
  float cmax = __uint_as_float(0x7F800000u);                  // +inf
  int cnt = 0;

  auto flushfn = [&]() {
#pragma unroll
    for (int e = 0; e < 8; ++e) {
      if (e < cnt) {
        u64 key = smem[tid * 9 + e];
        if (key < L[15]) {  // exact (d, idx) compare in key domain
#pragma unroll
          for (int s = 15; s >= 1; --s)
            L[s] = (key < L[s - 1]) ? L[s - 1] : ((key < L[s]) ? key : L[s]);
          L[0] = (key < L[0]) ? key : L[0];
        }
      }
    }
    cnt = 0;
    u32 hb = (u32)(L[15] >> 32);               // un-transform kth distance
    hb ^= (hb >= 0x80000000u) ? 0x80000000u : 0xFFFFFFFFu;
    cmax = __uint_as_float(hb);
  };

  const int base = wv * 1024;
#pragma unroll 8
  for (int i = 0; i < 1024; ++i) {
    const int pidx = base + i;
    float ptx = xb[pidx * 3 + 0], pty = xb[pidx * 3 + 1], ptz = xb[pidx * 3 + 2];
    float pv = ppb[pidx];
    float dot = __fadd_rn(__fadd_rn(__fmul_rn(qx, ptx), __fmul_rn(qy, pty)),
                          __fmul_rn(qz, ptz));
    float d = __fadd_rn(__fadd_rn(__fmul_rn(-2.0f, dot), qq), pv);
    if (d <= cmax) {  // <= admits exact ties; flush's exact compare filters
      u32 xb32 = __float_as_uint(d);
      xb32 ^= ((int)xb32 < 0) ? 0xFFFFFFFFu : 0x80000000u;  // orderable bits
      smem[tid * 9 + cnt] = ((u64)xb32 << 32) | (u32)pidx;
      ++cnt;
    }
    if (__any(cnt >= 8)) flushfn();  // wave-collective, converged flush
  }
  flushfn();
  __syncthreads();  // done with Bf region before overwriting as Ls
#pragma unroll
  for (int s = 0; s < 16; ++s) smem[tid * 16 + s] = L[s];
  __syncthreads();
  // 8-way merge of sorted lists -> global top-16 per query (one lane each)
  if (tid < 64) {
    u64 h[8]; int pos[8];
#pragma unroll
    for (int w = 0; w < 8; ++w) { h[w] = smem[(w * 64 + tid) * 16]; pos[w] = 1; }
    int outv[16];
#pragma unroll
    for (int r = 0; r < 16; ++r) {
      u64 mv = h[0]; int mw = 0;
#pragma unroll
      for (int w = 1; w < 8; ++w) {
        if (h[w] < mv) { mv = h[w]; mw = w; }
      }
      outv[r] = (int)(mv & 0xFFFFFFFFULL);
#pragma unroll
      for (int w = 0; w < 8; ++w) {
        if (w == mw) {
          h[w] = (pos[w] < 16) ? smem[(w * 64 + tid) * 16 + pos[w]]
                               : 0xFFFFFFFFFFFFFFFFULL;
          pos[w]++;
        }
      }
    }
    int* dst = knn_idx + ((size_t)b * NPOINT + qbase + tid) * KNN;
#pragma unroll
    for (int r = 0; r < 16; r += 4)
      *(int4*)(dst + r) = make_int4(outv[r], outv[r + 1], outv[r + 2], outv[r + 3]);
  }
}

// ---------------------------------------------------------------------------
// Stats: recompute h rows, accumulate per-channel sum & sumsq.
// Lane-halving butterfly: 63 shuffles reduce 64 values across the wave;
// lane l ends holding the wave total of value l. Then block LDS combine and
// one f64 atomic per channel-stat per block.
// ---------------------------------------------------------------------------
__global__ __launch_bounds__(256) void stats_kernel(const float* __restrict__ feature,
                                                    const float* __restrict__ Wm,
                                                    const float* __restrict__ bias,
                                                    const int* __restrict__ knn_idx,
                                                    double* __restrict__ stats) {
  __shared__ float s_part[256];
  const int tid = threadIdx.x;
  const int lane = tid & 63;
  const int wv = tid >> 6;
  const int tbase = blockIdx.x * 256 + tid;  // 0..65535; rows strided by 65536
  for (int chunk = 0; chunk < 4; ++chunk) {
    const int c0 = chunk * 32;
    float V[64];
#pragma unroll
    for (int j = 0; j < 64; ++j) V[j] = 0.f;
    for (int rr = 0; rr < 4; ++rr) {
      const int row = tbase + rr * 65536;
      const int bb = row >> 15;  // 32768 rows per batch
      const int nbr = knn_idx[row];
      const float4* fp = (const float4*)(feature + ((size_t)bb * NPTS + nbr) * CIN);
      float acc[32];
#pragma unroll
      for (int j = 0; j < 32; ++j) acc[j] = bias[c0 + j];
      for (int cb = 0; cb < 8; ++cb) {  // rolled: small I-footprint, W via s_load
        float4 fa = fp[cb * 2 + 0], fb2 = fp[cb * 2 + 1];
        float fr[8] = {fa.x, fa.y, fa.z, fa.w, fb2.x, fb2.y, fb2.z, fb2.w};
#pragma unroll
        for (int cc = 0; cc < 8; ++cc) {
          const int c = cb * 8 + cc;
#pragma unroll
          for (int j = 0; j < 32; ++j)
            acc[j] = fmaf(fr[cc], Wm[c * COUT + c0 + j], acc[j]);
        }
      }
#pragma unroll
      for (int j = 0; j < 32; ++j) {
        V[j] += acc[j];
        V[32 + j] = fmaf(acc[j], acc[j], V[32 + j]);
      }
    }
    // halving butterfly: send the half you give away, keep+add the other
#pragma unroll
    for (int o = 32; o >= 1; o >>= 1) {
      const bool hi = (lane & o) != 0;
#pragma unroll
      for (int j = 0; j < o; ++j) {
        float keep = hi ? V[o + j] : V[j];
        float send = hi ? V[j] : V[o + j];
        V[j] = keep + __shfl_xor(send, o);
      }
    }
    s_part[wv * 64 + lane] = V[0];
    __syncthreads();
    if (tid < 64) {
      float tot = s_part[tid] + s_part[64 + tid] + s_part[128 + tid] + s_part[192 + tid];
      int addr = (tid < 32) ? (c0 + tid) : (COUT + c0 + (tid - 32));
      atomicAdd(stats + addr, (double)tot);
    }
    __syncthreads();
  }
}

// ---------------------------------------------------------------------------
// Apply: recompute h, BN-normalize (scale/shift from double stats), ReLU,
// max over K=16 via shfl within 16-lane groups, write new_feature.
// block = 16 queries x 16 k.
// ---------------------------------------------------------------------------
__global__ __launch_bounds__(256) void apply_kernel(const float* __restrict__ feature,
                                                    const float* __restrict__ Wm,
                                                    const float* __restrict__ bias,
                                                    const float* __restrict__ gamma,
                                                    const float* __restrict__ beta,
                                                    const int* __restrict__ knn_idx,
                                                    const double* __restrict__ stats,
                                                    float* __restrict__ out_feat) {
  __shared__ float s_sc[COUT], s_sh[COUT];
  const int tid = threadIdx.x;
  if (tid < COUT) {
    const double inv_n = 1.0 / (double)(BATCH * NPOINT * KNN);
    double mean = stats[tid] * inv_n;
    double var = stats[COUT + tid] * inv_n - mean * mean;
    double s = (double)gamma[tid] / sqrt(var + 1e-5);
    s_sc[tid] = (float)s;
    s_sh[tid] = (float)((double)beta[tid] - mean * s);
  }
  __syncthreads();
  const int k = tid & 15;
  const int qg = blockIdx.x * 16 + (tid >> 4);
  const int bb = qg >> 11;
  const int nbr = knn_idx[qg * KNN + k];
  const float4* fp = (const float4*)(feature + ((size_t)bb * NPTS + nbr) * CIN);
  float* outp = out_feat + (size_t)qg * COUT;
  for (int chunk = 0; chunk < 4; ++chunk) {
    const int c0 = chunk * 32;
    float acc[32];
#pragma unroll
    for (int j = 0; j < 32; ++j) acc[j] = bias[c0 + j];
    for (int cb = 0; cb < 8; ++cb) {
      float4 fa = fp[cb * 2 + 0], fb2 = fp[cb * 2 + 1];
      float fr[8] = {fa.x, fa.y, fa.z, fa.w, fb2.x, fb2.y, fb2.z, fb2.w};
#pragma unroll
      for (int cc = 0; cc < 8; ++cc) {
        const int c = cb * 8 + cc;
#pragma unroll
        for (int j = 0; j < 32; ++j)
          acc[j] = fmaf(fr[cc], Wm[c * COUT + c0 + j], acc[j]);
      }
    }
#pragma unroll
    for (int j = 0; j < 32; ++j) {
      float n = fmaxf(fmaf(acc[j], s_sc[c0 + j], s_sh[c0 + j]), 0.0f);
#pragma unroll
      for (int off = 8; off >= 1; off >>= 1)  // max over the 16-lane k-group
        n = fmaxf(n, __shfl_xor(n, off));
      acc[j] = n;
    }
    if (k == 0) {
#pragma unroll
      for (int j = 0; j < 32; j += 4)
        *(float4*)(outp + c0 + j) = make_float4(acc[j], acc[j + 1], acc[j + 2], acc[j + 3]);
    }
  }
}

// ---------------------------------------------------------------------------
extern "C" void kernel_launch(void* const* d_in, const int* in_sizes, int n_in,
                              void* d_out, int out_size, void* d_ws, size_t ws_size,
                              hipStream_t stream) {
  (void)in_sizes; (void)n_in; (void)out_size; (void)ws_size;
  const float* xyz = (const float*)d_in[0];
  const float* feature = (const float*)d_in[1];
  const float* Wm = (const float*)d_in[2];
  const float* bias = (const float*)d_in[3];
  const float* gamma = (const float*)d_in[4];
  const float* beta = (const float*)d_in[5];
  // npoint (d_in[6]) fixed at 2048

  float* out_xyz = (float*)d_out;                            // [8,2048,3]
  float* out_feat = (float*)d_out + (size_t)BATCH * NPOINT * 3;  // [8,2048,128]

  // workspace: knn_idx 1MB | stats 2KB (@1MB) | pp 256KB (@1MB+4KB)
  int* knn_idx = (int*)d_ws;
  double* stats = (double*)((char*)d_ws + (1 << 20));
  float* pp = (float*)((char*)d_ws + (1 << 20) + 4096);

  pp_kernel<<<dim3(256), dim3(256), 0, stream>>>(xyz, pp);
  fps_kernel<<<dim3(BATCH), dim3(FPS_T), 0, stream>>>(xyz, out_xyz);
  knn_kernel<<<dim3(256), dim3(512), 0, stream>>>(xyz, pp, out_xyz, knn_idx);
  (void)hipMemsetAsync(stats, 0, 2 * COUT * sizeof(double), stream);
  stats_kernel<<<dim3(256), dim3(256), 0, stream>>>(feature, Wm, bias, knn_idx, stats);
  apply_kernel<<<dim3(1024), dim3(256), 0, stream>>>(feature, Wm, bias, gamma, beta,
                                                     knn_idx, stats, out_feat);
}

// Round 8
// 2345.172 us; speedup vs baseline: 1.1423x; 1.1423x over previous
//
#include <hip/hip_runtime.h>

typedef unsigned long long u64;
typedef unsigned int u32;
typedef float f32x2 __attribute__((ext_vector_type(2)));

constexpr int BATCH  = 8;
constexpr int NPTS   = 8192;
constexpr int CIN    = 64;
constexpr int COUT   = 128;
constexpr int NPOINT = 2048;
constexpr int KNN    = 16;

// ---------------------------------------------------------------------------
// pp kernel: per-point squared norm, same op order as reference sum(xyz**2)
// ---------------------------------------------------------------------------
__global__ __launch_bounds__(256) void pp_kernel(const float* __restrict__ xyz,
                                                 float* __restrict__ pp) {
  int i = blockIdx.x * 256 + threadIdx.x;  // 0..65535 (B*N)
  float x = xyz[i * 3 + 0], y = xyz[i * 3 + 1], z = xyz[i * 3 + 2];
  pp[i] = __fadd_rn(__fadd_rn(__fmul_rn(x, x), __fmul_rn(y, y)), __fmul_rn(z, z));
}

// ---------------------------------------------------------------------------
// FPS v7 = R4's v3 (best measured: 1904us) + two stall-targeted edits ONLY.
// R7 lesson: launch_bounds(256,1) caused LDS spill (LDS +4KB, 254K bank
// conflicts) with VGPR stuck at 132 -> reverted. R2-R7 A/B table: generic
// f32x2 + fused argmax + 256thr wins; asm-pk / two-pass / 512thr / min-waves
// all regressed. R4 budget: 2232cy/step = ~1200 issue + ~1000 stall.
// Edit 1: sOut LDS staging (in-loop global store forced vmcnt(0) drain at
//         every barrier on wave 0 -> everyone waits; now one dump at end).
// Edit 2: argmax dep-chain split in two (pairs 0-7 / 8-15, chain-0 priority
//         on tie == smallest index wins == jnp.argmax; halves the 16-deep
//         cndmask dependency that 1 wave/SIMD cannot hide).
// Distance math: generic f32x2 ops (compiler-scheduled), contract(off) so
// no FMA contraction -> selection bits match XLA elementwise
// (dx*dx+dy*dy)+dz*dz exactly (validated absmax=0.015625 since R1).
// Key = (d_bits<<32 | 8191-idx): u64 max == (max d, tie -> min idx).
// DPP directional reduce -> lane63; parity-slot single barrier per step.
// ---------------------------------------------------------------------------
constexpr int FPS_T = 256;
constexpr int FPS_PAIRS = NPTS / FPS_T / 2;  // 16 pairs = 32 pts/thread

#define DPP_LVL(CTRL)                                                          \
  {                                                                            \
    u32 hi_o = (u32)__builtin_amdgcn_update_dpp((int)khi, (int)khi, (CTRL),    \
                                                0xf, 0xf, false);              \
    u32 lo_o = (u32)__builtin_amdgcn_update_dpp((int)klo, (int)klo, (CTRL),    \
                                                0xf, 0xf, false);              \
    bool gt = (hi_o > khi) || ((hi_o == khi) && (lo_o > klo));                 \
    khi = gt ? hi_o : khi;                                                     \
    klo = gt ? lo_o : klo;                                                     \
  }

__global__ __launch_bounds__(256) void fps_kernel(const float* __restrict__ xyz,
                                                  float* __restrict__ out_xyz) {
#pragma clang fp contract(off)
  __shared__ float4 sP[NPTS];          // 128 KB
  __shared__ float sOut[NPOINT * 3];   // 24 KB (total ~152.1 KB of 160)
  __shared__ u64 sKey[2][4];
  const int b = blockIdx.x;
  const int t = threadIdx.x;
  const int lane = t & 63;
  const int wv = t >> 6;
  const float* xb = xyz + (size_t)b * NPTS * 3;
  f32x2 px2[FPS_PAIRS], py2[FPS_PAIRS], pz2[FPS_PAIRS], pd2[FPS_PAIRS];
#pragma unroll
  for (int jp = 0; jp < FPS_PAIRS; ++jp) {
    int p0 = t + (2 * jp) * FPS_T;      // idx ascending with (jp, half)
    int p1 = t + (2 * jp + 1) * FPS_T;
    float x0 = xb[p0 * 3 + 0], y0 = xb[p0 * 3 + 1], z0 = xb[p0 * 3 + 2];
    float x1 = xb[p1 * 3 + 0], y1 = xb[p1 * 3 + 1], z1 = xb[p1 * 3 + 2];
    px2[jp] = (f32x2){x0, x1};
    py2[jp] = (f32x2){y0, y1};
    pz2[jp] = (f32x2){z0, z1};
    pd2[jp] = (f32x2){1e10f, 1e10f};
    sP[p0] = make_float4(x0, y0, z0, 0.f);
    sP[p1] = make_float4(x1, y1, z1, 0.f);
  }
  float cx = xb[0], cy = xb[1], cz = xb[2];  // seed point index 0
  float* outx = out_xyz + (size_t)b * NPOINT * 3;
  __syncthreads();
  for (int it = 0; it < NPOINT; ++it) {
    if (t == 0) {  // scan emits the carry (current farthest); LDS-staged
      sOut[it * 3 + 0] = cx; sOut[it * 3 + 1] = cy; sOut[it * 3 + 2] = cz;
    }
    const f32x2 cx2 = {cx, cx}, cy2 = {cy, cy}, cz2 = {cz, cz};
    // two independent fused argmax chains (pairs 0-7 / 8-15): halves the
    // cndmask dependency depth that 1 wave/SIMD cannot hide
    float bda = -1.0f; int bja = 0;
    float bdb = -1.0f; int bjb = 16;
#pragma unroll
    for (int jp = 0; jp < FPS_PAIRS; ++jp) {
      f32x2 dx = px2[jp] - cx2;
      f32x2 dy = py2[jp] - cy2;
      f32x2 dz = pz2[jp] - cz2;
      f32x2 d = (dx * dx + dy * dy) + dz * dz;  // contract(off): no FMA
      f32x2 nd = __builtin_elementwise_min(pd2[jp], d);
      pd2[jp] = nd;
      if (jp < 8) {  // compile-time split (full unroll)
        if (nd.x > bda) { bda = nd.x; bja = 2 * jp; }
        if (nd.y > bda) { bda = nd.y; bja = 2 * jp + 1; }
      } else {
        if (nd.x > bdb) { bdb = nd.x; bjb = 2 * jp; }
        if (nd.y > bdb) { bdb = nd.y; bjb = 2 * jp + 1; }
      }
    }
    // merge: strict > from chain b -> tie goes to chain a (smaller index),
    // matching jnp.argmax smallest-index tie rule (idx ascending in j)
    float bd = bda; int bj = bja;
    if (bdb > bda) { bd = bdb; bj = bjb; }
    const int bi0 = t + bj * FPS_T;
    u32 khi = __float_as_uint(bd);    // d>=0 -> bits monotone in d
    u32 klo = (u32)(8191 - bi0);      // tie -> larger klo == smaller idx
    // 6-level DPP directional max-reduce; full-wave max lands in lane 63
    DPP_LVL(0x111)  // row_shr:1
    DPP_LVL(0x112)  // row_shr:2
    DPP_LVL(0x114)  // row_shr:4
    DPP_LVL(0x118)  // row_shr:8
    DPP_LVL(0x142)  // row_bcast15
    DPP_LVL(0x143)  // row_bcast31
    const int par = it & 1;
    if (lane == 63) sKey[par][wv] = ((u64)khi << 32) | klo;
    __syncthreads();
    // all threads redundantly merge the 4 wave candidates (single barrier;
    // parity slots make the pipeline race-free)
    u64 k0 = sKey[par][0];
    u64 k1 = sKey[par][1];
    u64 k2 = sKey[par][2];
    u64 k3 = sKey[par][3];
    if (k1 > k0) k0 = k1;
    if (k3 > k2) k2 = k3;
    if (k2 > k0) k0 = k2;
    const int bi = 8191 - (int)(u32)(k0 & 0xFFFFFFFFu);
    float4 c4 = sP[bi];  // one ds_read_b128 broadcast
    cx = c4.x; cy = c4.y; cz = c4.z;
  }
  __syncthreads();
  // one coalesced dump of the staged output
  for (int i = t; i < NPOINT * 3; i += FPS_T) outx[i] = sOut[i];
}

// ---------------------------------------------------------------------------
// kNN: block = 64 queries (one batch) x 8 chunk-waves (1024 pts each).
// Point data is wave-uniform -> scalar loads. Per-lane sorted top-16 in regs
// (packed u64: orderable-float-bits<<32 | idx, so compare = (d, idx) lexico),
// with deferred LDS candidate buffer + wave-collective flush to avoid
// per-point divergent insert ladders. Distance mimics reference expansion
// -2*q.p + |q|^2 + |p|^2 with rn ops.
// ---------------------------------------------------------------------------
__global__ __launch_bounds__(512) void knn_kernel(const float* __restrict__ xyz,
                                                  const float* __restrict__ pp,
                                                  const float* __restrict__ new_xyz,
                                                  int* __restrict__ knn_idx) {
  __shared__ u64 smem[8192];  // 64KB. scan: Bf[512][9] (padded); merge: Ls[512][16]
  const int tid = threadIdx.x;
  const int lane = tid & 63;
  const int wv = __builtin_amdgcn_readfirstlane(tid >> 6);  // chunk id, forced scalar
  const int bid = blockIdx.x;
  const int b = bid >> 5;               // 32 query-blocks per batch
  const int qbase = (bid & 31) * 64;
  const int q = qbase + lane;
  const float* xb = xyz + (size_t)b * NPTS * 3;
  const float* ppb = pp + (size_t)b * NPTS;
  const float* nq = new_xyz + ((size_t)b * NPOINT + q) * 3;
  float qx = nq[0], qy = nq[1], qz = nq[2];
  float qq = __fadd_rn(__fadd_rn(__fmul_rn(qx, qx), __fmul_rn(qy, qy)),
                       __fmul_rn(qz, qz));

  u64 L[16];
#pragma unroll
  for (int s = 0; s < 16; ++s) L[s] = 0xFF800000FFFFFFFFULL;  // +inf sentinel
  float cmax = __uint_as_float(0x7F800000u);                  // +inf
  int cnt = 0;

  auto flushfn = [&]() {
#pragma unroll
    for (int e = 0; e < 8; ++e) {
      if (e < cnt) {
        u64 key = smem[tid * 9 + e];
        if (key < L[15]) {  // exact (d, idx) compare in key domain
#pragma unroll
          for (int s = 15; s >= 1; --s)
            L[s] = (key < L[s - 1]) ? L[s - 1] : ((key < L[s]) ? key : L[s]);
          L[0] = (key < L[0]) ? key : L[0];
        }
      }
    }
    cnt = 0;
    u32 hb = (u32)(L[15] >> 32);               // un-transform kth distance
    hb ^= (hb >= 0x80000000u) ? 0x80000000u : 0xFFFFFFFFu;
    cmax = __uint_as_float(hb);
  };

  const int base = wv * 1024;
#pragma unroll 8
  for (int i = 0; i < 1024; ++i) {
    const int pidx = base + i;
    float ptx = xb[pidx * 3 + 0], pty = xb[pidx * 3 + 1], ptz = xb[pidx * 3 + 2];
    float pv = ppb[pidx];
    float dot = __fadd_rn(__fadd_rn(__fmul_rn(qx, ptx), __fmul_rn(qy, pty)),
                          __fmul_rn(qz, ptz));
    float d = __fadd_rn(__fadd_rn(__fmul_rn(-2.0f, dot), qq), pv);
    if (d <= cmax) {  // <= admits exact ties; flush's exact compare filters
      u32 xb32 = __float_as_uint(d);
      xb32 ^= ((int)xb32 < 0) ? 0xFFFFFFFFu : 0x80000000u;  // orderable bits
      smem[tid * 9 + cnt] = ((u64)xb32 << 32) | (u32)pidx;
      ++cnt;
    }
    if (__any(cnt >= 8)) flushfn();  // wave-collective, converged flush
  }
  flushfn();
  __syncthreads();  // done with Bf region before overwriting as Ls
#pragma unroll
  for (int s = 0; s < 16; ++s) smem[tid * 16 + s] = L[s];
  __syncthreads();
  // 8-way merge of sorted lists -> global top-16 per query (one lane each)
  if (tid < 64) {
    u64 h[8]; int pos[8];
#pragma unroll
    for (int w = 0; w < 8; ++w) { h[w] = smem[(w * 64 + tid) * 16]; pos[w] = 1; }
    int outv[16];
#pragma unroll
    for (int r = 0; r < 16; ++r) {
      u64 mv = h[0]; int mw = 0;
#pragma unroll
      for (int w = 1; w < 8; ++w) {
        if (h[w] < mv) { mv = h[w]; mw = w; }
      }
      outv[r] = (int)(mv & 0xFFFFFFFFULL);
#pragma unroll
      for (int w = 0; w < 8; ++w) {
        if (w == mw) {
          h[w] = (pos[w] < 16) ? smem[(w * 64 + tid) * 16 + pos[w]]
                               : 0xFFFFFFFFFFFFFFFFULL;
          pos[w]++;
        }
      }
    }
    int* dst = knn_idx + ((size_t)b * NPOINT + qbase + tid) * KNN;
#pragma unroll
    for (int r = 0; r < 16; r += 4)
      *(int4*)(dst + r) = make_int4(outv[r], outv[r + 1], outv[r + 2], outv[r + 3]);
  }
}

// ---------------------------------------------------------------------------
// Stats: recompute h rows, accumulate per-channel sum & sumsq.
// Lane-halving butterfly: 63 shuffles reduce 64 values across the wave;
// lane l ends holding the wave total of value l. Then block LDS combine and
// one f64 atomic per channel-stat per block.
// ---------------------------------------------------------------------------
__global__ __launch_bounds__(256) void stats_kernel(const float* __restrict__ feature,
                                                    const float* __restrict__ Wm,
                                                    const float* __restrict__ bias,
                                                    const int* __restrict__ knn_idx,
                                                    double* __restrict__ stats) {
  __shared__ float s_part[256];
  const int tid = threadIdx.x;
  const int lane = tid & 63;
  const int wv = tid >> 6;
  const int tbase = blockIdx.x * 256 + tid;  // 0..65535; rows strided by 65536
  for (int chunk = 0; chunk < 4; ++chunk) {
    const int c0 = chunk * 32;
    float V[64];
#pragma unroll
    for (int j = 0; j < 64; ++j) V[j] = 0.f;
    for (int rr = 0; rr < 4; ++rr) {
      const int row = tbase + rr * 65536;
      const int bb = row >> 15;  // 32768 rows per batch
      const int nbr = knn_idx[row];
      const float4* fp = (const float4*)(feature + ((size_t)bb * NPTS + nbr) * CIN);
      float acc[32];
#pragma unroll
      for (int j = 0; j < 32; ++j) acc[j] = bias[c0 + j];
      for (int cb = 0; cb < 8; ++cb) {  // rolled: small I-footprint, W via s_load
        float4 fa = fp[cb * 2 + 0], fb2 = fp[cb * 2 + 1];
        float fr[8] = {fa.x, fa.y, fa.z, fa.w, fb2.x, fb2.y, fb2.z, fb2.w};
#pragma unroll
        for (int cc = 0; cc < 8; ++cc) {
          const int c = cb * 8 + cc;
#pragma unroll
          for (int j = 0; j < 32; ++j)
            acc[j] = fmaf(fr[cc], Wm[c * COUT + c0 + j], acc[j]);
        }
      }
#pragma unroll
      for (int j = 0; j < 32; ++j) {
        V[j] += acc[j];
        V[32 + j] = fmaf(acc[j], acc[j], V[32 + j]);
      }
    }
    // halving butterfly: send the half you give away, keep+add the other
#pragma unroll
    for (int o = 32; o >= 1; o >>= 1) {
      const bool hi = (lane & o) != 0;
#pragma unroll
      for (int j = 0; j < o; ++j) {
        float keep = hi ? V[o + j] : V[j];
        float send = hi ? V[j] : V[o + j];
        V[j] = keep + __shfl_xor(send, o);
      }
    }
    s_part[wv * 64 + lane] = V[0];
    __syncthreads();
    if (tid < 64) {
      float tot = s_part[tid] + s_part[64 + tid] + s_part[128 + tid] + s_part[192 + tid];
      int addr = (tid < 32) ? (c0 + tid) : (COUT + c0 + (tid - 32));
      atomicAdd(stats + addr, (double)tot);
    }
    __syncthreads();
  }
}

// ---------------------------------------------------------------------------
// Apply: recompute h, BN-normalize (scale/shift from double stats), ReLU,
// max over K=16 via shfl within 16-lane groups, write new_feature.
// block = 16 queries x 16 k.
// ---------------------------------------------------------------------------
__global__ __launch_bounds__(256) void apply_kernel(const float* __restrict__ feature,
                                                    const float* __restrict__ Wm,
                                                    const float* __restrict__ bias,
                                                    const float* __restrict__ gamma,
                                                    const float* __restrict__ beta,
                                                    const int* __restrict__ knn_idx,
                                                    const double* __restrict__ stats,
                                                    float* __restrict__ out_feat) {
  __shared__ float s_sc[COUT], s_sh[COUT];
  const int tid = threadIdx.x;
  if (tid < COUT) {
    const double inv_n = 1.0 / (double)(BATCH * NPOINT * KNN);
    double mean = stats[tid] * inv_n;
    double var = stats[COUT + tid] * inv_n - mean * mean;
    double s = (double)gamma[tid] / sqrt(var + 1e-5);
    s_sc[tid] = (float)s;
    s_sh[tid] = (float)((double)beta[tid] - mean * s);
  }
  __syncthreads();
  const int k = tid & 15;
  const int qg = blockIdx.x * 16 + (tid >> 4);
  const int bb = qg >> 11;
  const int nbr = knn_idx[qg * KNN + k];
  const float4* fp = (const float4*)(feature + ((size_t)bb * NPTS + nbr) * CIN);
  float* outp = out_feat + (size_t)qg * COUT;
  for (int chunk = 0; chunk < 4; ++chunk) {
    const int c0 = chunk * 32;
    float acc[32];
#pragma unroll
    for (int j = 0; j < 32; ++j) acc[j] = bias[c0 + j];
    for (int cb = 0; cb < 8; ++cb) {
      float4 fa = fp[cb * 2 + 0], fb2 = fp[cb * 2 + 1];
      float fr[8] = {fa.x, fa.y, fa.z, fa.w, fb2.x, fb2.y, fb2.z, fb2.w};
#pragma unroll
      for (int cc = 0; cc < 8; ++cc) {
        const int c = cb * 8 + cc;
#pragma unroll
        for (int j = 0; j < 32; ++j)
          acc[j] = fmaf(fr[cc], Wm[c * COUT + c0 + j], acc[j]);
      }
    }
#pragma unroll
    for (int j = 0; j < 32; ++j) {
      float n = fmaxf(fmaf(acc[j], s_sc[c0 + j], s_sh[c0 + j]), 0.0f);
#pragma unroll
      for (int off = 8; off >= 1; off >>= 1)  // max over the 16-lane k-group
        n = fmaxf(n, __shfl_xor(n, off));
      acc[j] = n;
    }
    if (k == 0) {
#pragma unroll
      for (int j = 0; j < 32; j += 4)
        *(float4*)(outp + c0 + j) = make_float4(acc[j], acc[j + 1], acc[j + 2], acc[j + 3]);
    }
  }
}

// ---------------------------------------------------------------------------
extern "C" void kernel_launch(void* const* d_in, const int* in_sizes, int n_in,
                              void* d_out, int out_size, void* d_ws, size_t ws_size,
                              hipStream_t stream) {
  (void)in_sizes; (void)n_in; (void)out_size; (void)ws_size;
  const float* xyz = (const float*)d_in[0];
  const float* feature = (const float*)d_in[1];
  const float* Wm = (const float*)d_in[2];
  const float* bias = (const float*)d_in[3];
  const float* gamma = (const float*)d_in[4];
  const float* beta = (const float*)d_in[5];
  // npoint (d_in[6]) fixed at 2048

  float* out_xyz = (float*)d_out;                            // [8,2048,3]
  float* out_feat = (float*)d_out + (size_t)BATCH * NPOINT * 3;  // [8,2048,128]

  // workspace: knn_idx 1MB | stats 2KB (@1MB) | pp 256KB (@1MB+4KB)
  int* knn_idx = (int*)d_ws;
  double* stats = (double*)((char*)d_ws + (1 << 20));
  float* pp = (float*)((char*)d_ws + (1 << 20) + 4096);

  pp_kernel<<<dim3(256), dim3(256), 0, stream>>>(xyz, pp);
  fps_kernel<<<dim3(BATCH), dim3(FPS_T), 0, stream>>>(xyz, out_xyz);
  knn_kernel<<<dim3(256), dim3(512), 0, stream>>>(xyz, pp, out_xyz, knn_idx);
  (void)hipMemsetAsync(stats, 0, 2 * COUT * sizeof(double), stream);
  stats_kernel<<<dim3(256), dim3(256), 0, stream>>>(feature, Wm, bias, knn_idx, stats);
  apply_kernel<<<dim3(1024), dim3(256), 0, stream>>>(feature, Wm, bias, gamma, beta,
                                                     knn_idx, stats, out_feat);
}